// Round 4
// baseline (836.626 us; speedup 1.0000x reference)
//
#include <hip/hip_runtime.h>
#include <math.h>

typedef _Float16 h16;
typedef h16  h16x8 __attribute__((ext_vector_type(8)));
typedef h16  h16x4 __attribute__((ext_vector_type(4)));
typedef float f32x4 __attribute__((ext_vector_type(4)));

// ---------------- workspace layout (bytes) ----------------
// MH/ML : fp16 split of M [32 b][1024 j][256 d] (x2 zero-padded to 256)
// UHt/ULt: fp16 split of (U^T * 4) [2 h][256 d][256 c]   (*4 = 1/16 * 64 prescale)
// rmax_all/rmax_hi: [64 hb][1024] f32 ; pcm: [64 hb][16 rb][1024] f32
// m0key: ordered-int encoding of raw global min of head-0 K
#define MH_OFF   ((size_t)0)
#define ML_OFF   (MH_OFF + 16777216)
#define UHT_OFF  (ML_OFF + 16777216)
#define ULT_OFF  (UHT_OFF + 262144)
#define RMA_OFF  (ULT_OFF + 262144)
#define RMH_OFF  (RMA_OFF + 262144)
#define PCM_OFF  (RMH_OFF + 262144)
#define M0_OFF   (PCM_OFF + 4194304)

// Fully-converged Newton solve of y^3/3 + y = x (nonsat_activation limit).
// Strictly monotone -> commutes with max/min (applied post-reduction).
__device__ __forceinline__ float nonsat(float x) {
    float y = x;
#pragma unroll
    for (int i = 0; i < 24; ++i) {
        float y2 = y * y;
        y = fmaf(0.66666667f * y, y2, x) / (y2 + 1.0f);
    }
    return y;
}

// monotone float->int key (signed-int compare order == float order, no NaNs)
__device__ __forceinline__ int fkey(float f) {
    const int i = __float_as_int(f);
    return (i >= 0) ? i : (i ^ 0x7fffffff);
}
__device__ __forceinline__ float funkey(int k) {
    return __int_as_float((k >= 0) ? k : (k ^ 0x7fffffff));
}

// ---------------------------------------------------------------------------
// k_prep: fp16 hi/lo split of virtual M (x2 zero-padded) and of U^T*4.
// Also zeroes d_out (k_fin accumulates with atomicAdd) and inits m0key.
// ---------------------------------------------------------------------------
__global__ void k_prep(const float* __restrict__ x1, const float* __restrict__ x2,
                       const float* __restrict__ U, h16* __restrict__ MH,
                       h16* __restrict__ ML, h16* __restrict__ UHt,
                       h16* __restrict__ ULt, int* __restrict__ m0key,
                       float* __restrict__ out) {
    const int gid = blockIdx.x * 256 + threadIdx.x;
    if (blockIdx.x < 8192) {
        const int g  = gid;              // (b, j, d4): 32*1024*64 groups
        const int d4 = (g & 63) * 4;
        const int j  = (g >> 6) & 1023;
        const int b  = g >> 16;
        float v[4];
        if (j < 512) {
            const float4 p = *(const float4*)(x1 + ((size_t)(b * 512 + j) * 256 + d4));
            v[0] = p.x; v[1] = p.y; v[2] = p.z; v[3] = p.w;
        } else if (d4 < 192) {           // 192 % 4 == 0: all four in-range
            const float4 p = *(const float4*)(x2 +
                (size_t)(b * 512 + (j - 512)) * 192 + d4);
            v[0] = p.x; v[1] = p.y; v[2] = p.z; v[3] = p.w;
        } else {
            v[0] = v[1] = v[2] = v[3] = 0.0f;
        }
        h16x4 hh, ll;
#pragma unroll
        for (int k = 0; k < 4; ++k) {
            const h16 hi = (h16)v[k];
            hh[k] = hi;
            ll[k] = (h16)(v[k] - (float)hi);
        }
        const size_t o = (size_t)g * 4;
        *(h16x4*)&MH[o] = hh;
        *(h16x4*)&ML[o] = ll;
    } else if (blockIdx.x < 8320) {
        const int g  = gid - 8192 * 256; // U^T: 2*256*64 groups
        const int c4 = (g & 63) * 4;
        const int d  = (g >> 6) & 255;
        const int h  = g >> 14;
        h16x4 hh, ll;
#pragma unroll
        for (int k = 0; k < 4; ++k) {
            const float v = U[((size_t)h * 256 + c4 + k) * 256 + d] * 4.0f;
            const h16 hi = (h16)v;
            hh[k] = hi;
            ll[k] = (h16)(v - (float)hi);
        }
        const size_t o = ((size_t)h * 256 + d) * 256 + c4;
        *(h16x4*)&UHt[o] = hh;
        *(h16x4*)&ULt[o] = ll;
    } else {
        const int z = gid - 8320 * 256;  // 32768 output floats to zero
        out[z] = 0.0f;
        if (z == 0) *m0key = 0x7fffffff; // +max key
    }
}

// ---------------------------------------------------------------------------
// k_main (R14 = R13 + red-size fix): same 64-row tile / same math, re-waved
// for occupancy. R3 post-mortem: R13's NaN was an LDS overflow — red stayed
// [1024+16] while the 16-wave rowmax indexing (jt*16+w)*64+row reaches 2047,
// and gmin at red[1024+w] collided with the jt=1 region. Fixed: red[2048+16],
// gmin at red[2048+w]. LDS = 64K (sP) + 8.25K (red) = 73.8 KB -> 1 block/CU
// at 1024 thr = 4 waves/SIMD (launch_bounds(1024,4) caps VGPR at 128).
// R2 diagnosis stands: latency-bound (MfmaUtil 24, VALU 12, HBM 2.5%); the
// fix is wave-level interleave (4-way vs 2-way), not register pipelining
// (R1 proved that spills). Phase B j-splits 16 ways: acc[4][2] = 32 regs;
// per-wave arithmetic intensity and block-level traffic unchanged.
// Accumulation order per element unchanged -> bitwise-identical outputs.
// ---------------------------------------------------------------------------
__global__ __launch_bounds__(1024, 4)
void k_main(const h16* __restrict__ MH, const h16* __restrict__ ML,
            const h16* __restrict__ UHt, const h16* __restrict__ ULt,
            float* __restrict__ rmax_all, float* __restrict__ rmax_hi,
            float* __restrict__ pcm, int* __restrict__ m0key) {
    __shared__ __align__(16) h16 sP[2][64 * 256];  // P hi/lo, XOR-swizzled, 64 KB
    __shared__ float red[2048 + 16];               // 16 waves x 2 jt x 64 rows + gmin

    // XCD-affine swizzle (round-robin blk%8 -> XCD; bijective either way)
    const int n    = blockIdx.x;       // 1024
    const int x    = n & 7;            // presumed XCD
    const int s    = n >> 3;           // 0..127 slot on this XCD
    const int b    = x + 8 * (s >> 5); // 4 batches per XCD
    const int h    = (s >> 4) & 1;
    const int rblk = s & 15;
    const int hb   = h * 32 + b;
    const int r0   = rblk * 64;
    const int t    = threadIdx.x;
    const int w    = t >> 6;           // wave 0..15
    const int l    = t & 63;
    const int q    = l >> 4;           // quad -> A/B k-offset q*8 ; C row q*4+reg
    const int ln   = l & 15;           // A/B row ; C col

    // ---------------- Phase A ----------------
    // wave (wr,wc) = (w>>2, w&3): rows wr*16.., d-cols wc*64.. (acc[4] over tj)
    {
        const int wr = w >> 2, wc = w & 3;
        f32x4 acc[4];
        const f32x4 z4 = {0.f, 0.f, 0.f, 0.f};
#pragma unroll
        for (int j = 0; j < 4; ++j) acc[j] = z4;

        for (int kc = 0; kc < 8; ++kc) {
            const int c0 = kc * 32;
            h16x8 aH, aL, bH[4], bL[4];
            {
                const size_t off =
                    (size_t)(b * 1024 + r0 + wr * 16 + ln) * 256 + c0 + q * 8;
                aH = *(const h16x8*)&MH[off];
                aL = *(const h16x8*)&ML[off];
            }
#pragma unroll
            for (int tj = 0; tj < 4; ++tj) {
                const size_t off =
                    (size_t)(h * 256 + wc * 64 + tj * 16 + ln) * 256 + c0 + q * 8;
                bH[tj] = *(const h16x8*)&UHt[off];
                bL[tj] = *(const h16x8*)&ULt[off];
            }
#pragma unroll
            for (int tj = 0; tj < 4; ++tj)
                acc[tj] = __builtin_amdgcn_mfma_f32_16x16x32_f16(
                    aH, bH[tj], acc[tj], 0, 0, 0);
#pragma unroll
            for (int tj = 0; tj < 4; ++tj)
                acc[tj] = __builtin_amdgcn_mfma_f32_16x16x32_f16(
                    aL, bH[tj], acc[tj], 0, 0, 0);
#pragma unroll
            for (int tj = 0; tj < 4; ++tj)
                acc[tj] = __builtin_amdgcn_mfma_f32_16x16x32_f16(
                    aH, bL[tj], acc[tj], 0, 0, 0);
        }
        // split-store P' into sP, granule-swizzled: gran' = gran ^ (r&7)
#pragma unroll
        for (int tj = 0; tj < 4; ++tj)
#pragma unroll
            for (int reg = 0; reg < 4; ++reg) {
                const int r = wr * 16 + q * 4 + reg;   // C/D: row=q*4+reg
                const int d = wc * 64 + tj * 16 + ln;  //      col=ln
                const float v = acc[tj][reg];
                const h16 hi = (h16)v;
                const h16 lo = (h16)(v - (float)hi);
                const int off = r * 256 + (((d >> 3) ^ (r & 7)) << 3) + (d & 7);
                sP[0][off] = hi;
                sP[1][off] = lo;
            }
    }
    __syncthreads();

    // ---------------- Phase B ----------------
    // wave w covers j = jt*512 + w*32 .. +31 (acc[4 ti][2 tj]); all waves read
    // the full 64-row A panel from sP.
    float gmin = INFINITY;
    const int jts = (h == 1 && rblk < 8) ? 1 : 0;  // head-1 quadrant unused

    for (int jt = jts; jt < 2; ++jt) {
        const int jbase = jt * 512 + w * 32;
        const bool do_red = (rblk >= 8) || (jt == 1); // quadrant row/col maxes dead
        f32x4 acc[4][2];
        const f32x4 z4 = {0.f, 0.f, 0.f, 0.f};
#pragma unroll
        for (int i = 0; i < 4; ++i)
#pragma unroll
            for (int j = 0; j < 2; ++j) acc[i][j] = z4;

        for (int kc = 0; kc < 8; ++kc) {
            const int d0 = kc * 32;
            h16x8 aH[4], aL[4], bb[2];
            const int g = ((kc * 4 + q) ^ (ln & 7)) * 8;   // r&7 == ln&7
#pragma unroll
            for (int ti = 0; ti < 4; ++ti) {
                const int r = ti * 16 + ln;
                aH[ti] = *(const h16x8*)&sP[0][r * 256 + g];
                aL[ti] = *(const h16x8*)&sP[1][r * 256 + g];
            }
#pragma unroll
            for (int tj = 0; tj < 2; ++tj)
                bb[tj] = *(const h16x8*)&MH[
                    (size_t)(b * 1024 + jbase + tj * 16 + ln) * 256 + d0 + q * 8];
#pragma unroll
            for (int tj = 0; tj < 2; ++tj)
#pragma unroll
                for (int ti = 0; ti < 4; ++ti)
                    acc[ti][tj] = __builtin_amdgcn_mfma_f32_16x16x32_f16(
                        aH[ti], bb[tj], acc[ti][tj], 0, 0, 0);
#pragma unroll
            for (int tj = 0; tj < 2; ++tj)
#pragma unroll
                for (int ti = 0; ti < 4; ++ti)
                    acc[ti][tj] = __builtin_amdgcn_mfma_f32_16x16x32_f16(
                        aL[ti], bb[tj], acc[ti][tj], 0, 0, 0);
#pragma unroll
            for (int tj = 0; tj < 2; ++tj)
                bb[tj] = *(const h16x8*)&ML[
                    (size_t)(b * 1024 + jbase + tj * 16 + ln) * 256 + d0 + q * 8];
#pragma unroll
            for (int tj = 0; tj < 2; ++tj)
#pragma unroll
                for (int ti = 0; ti < 4; ++ti)
                    acc[ti][tj] = __builtin_amdgcn_mfma_f32_16x16x32_f16(
                        aH[ti], bb[tj], acc[ti][tj], 0, 0, 0);
        }

        if (do_red) {
            // rowmax for this jt -> red[(jt*16+w)*64 + row] (lane ln==0 writes)
#pragma unroll
            for (int ti = 0; ti < 4; ++ti)
#pragma unroll
                for (int reg = 0; reg < 4; ++reg) {
                    float m = fmaxf(acc[ti][0][reg], acc[ti][1][reg]);
                    m = fmaxf(m, __shfl_xor(m, 1));
                    m = fmaxf(m, __shfl_xor(m, 2));
                    m = fmaxf(m, __shfl_xor(m, 4));
                    m = fmaxf(m, __shfl_xor(m, 8));
                    if (ln == 0)
                        red[(jt * 16 + w) * 64 + ti * 16 + q * 4 + reg] = m;
                }
            // colmax over this block's 64 rows -> pcm (quads combined via shfl)
#pragma unroll
            for (int tj = 0; tj < 2; ++tj) {
                float m = -INFINITY;
#pragma unroll
                for (int ti = 0; ti < 4; ++ti)
#pragma unroll
                    for (int reg = 0; reg < 4; ++reg) m = fmaxf(m, acc[ti][tj][reg]);
                m = fmaxf(m, __shfl_xor(m, 16));
                m = fmaxf(m, __shfl_xor(m, 32));
                if (q == 0)
                    pcm[(size_t)(hb * 16 + rblk) * 1024 + jbase + tj * 16 + ln] =
                        m * 0.015625f;
            }
        }
        // raw min (only head 0 feeds mask_add)
        if (h == 0) {
#pragma unroll
            for (int ti = 0; ti < 4; ++ti)
#pragma unroll
                for (int tj = 0; tj < 2; ++tj)
#pragma unroll
                    for (int reg = 0; reg < 4; ++reg)
                        gmin = fminf(gmin, acc[ti][tj][reg]);
        }
    }

#pragma unroll
    for (int off = 1; off < 64; off <<= 1) gmin = fminf(gmin, __shfl_xor(gmin, off));
    if (l == 0) red[2048 + w] = gmin;
    __syncthreads();

    if (t < 64) {
        float hh = -INFINITY;
#pragma unroll
        for (int w2 = 0; w2 < 16; ++w2)
            hh = fmaxf(hh, red[(16 + w2) * 64 + t]);      // jt1 (j >= 512)
        if (rblk < 8) {
            // rows<512: k_fin only reads rmax_hi here (quadrant is masked)
            rmax_hi[(size_t)hb * 1024 + r0 + t] = hh * 0.015625f;
        } else {
            float a = hh;
#pragma unroll
            for (int w2 = 0; w2 < 16; ++w2)
                a = fmaxf(a, red[w2 * 64 + t]);           // jt0
            rmax_all[(size_t)hb * 1024 + r0 + t] = a * 0.015625f;
        }
    }
    if (t == 0 && hb < 32) {   // head 0 only feeds mask_add
        float g4 = red[2048];
#pragma unroll
        for (int i = 1; i < 16; ++i) g4 = fminf(g4, red[2048 + i]);
        atomicMin(m0key, fkey(g4 * 0.015625f));
    }
}

// ---------------------------------------------------------------------------
// k_fin: fused alpha (activation post-reduction) + softmax + chunked pooling.
// blk = hb*4 + seg*2 + chunk; 256 blocks x 256 thr; atomicAdd into zeroed out.
// ---------------------------------------------------------------------------
__global__ __launch_bounds__(256)
void k_fin(const float* __restrict__ rmax_all, const float* __restrict__ rmax_hi,
           const float* __restrict__ pcm, const int* __restrict__ m0key,
           const float* __restrict__ x1, const float* __restrict__ x2,
           float* __restrict__ out) {
    __shared__ float wv[512];
    __shared__ float sm[4], ss[4];
    const int blk   = blockIdx.x;
    const int chunk = blk & 1;
    const int seg   = (blk >> 1) & 1;
    const int hb    = blk >> 2;
    const int b     = hb & 31;
    const int t     = threadIdx.x;
    const float m0  = funkey(*m0key);

    float a2[2];
#pragma unroll
    for (int half = 0; half < 2; ++half) {
        const int i = seg * 512 + half * 256 + t;
        float rraw;
        if (seg == 0) rraw = fmaxf(m0, rmax_hi[(size_t)hb * 1024 + i]);
        else          rraw = rmax_all[(size_t)hb * 1024 + i];
        float call = -INFINITY, chi = -INFINITY;
#pragma unroll
        for (int rb = 0; rb < 16; ++rb) {
            const float v = pcm[(size_t)(hb * 16 + rb) * 1024 + i];
            call = fmaxf(call, v);
            if (rb >= 8) chi = fmaxf(chi, v);   // rows >= 512
        }
        const float craw = (seg == 0) ? fmaxf(m0, chi) : call;
        a2[half] = nonsat(rraw) + nonsat(craw);
    }
    const float a0 = a2[0], a1 = a2[1];

    float m = fmaxf(a0, a1);
#pragma unroll
    for (int off = 1; off < 64; off <<= 1) m = fmaxf(m, __shfl_xor(m, off));
    if ((t & 63) == 0) sm[t >> 6] = m;
    __syncthreads();
    const float amax = fmaxf(fmaxf(sm[0], sm[1]), fmaxf(sm[2], sm[3]));

    const float e0 = __expf(a0 - amax), e1 = __expf(a1 - amax);
    wv[t] = e0; wv[t + 256] = e1;
    float s = e0 + e1;
#pragma unroll
    for (int off = 1; off < 64; off <<= 1) s += __shfl_xor(s, off);
    if ((t & 63) == 0) ss[t >> 6] = s;
    __syncthreads();
    const float inv = 1.0f / (ss[0] + ss[1] + ss[2] + ss[3]);

    const int lo = chunk * 256;
    float acc = 0.0f;
    if (seg == 0) {
        const float* xp = x1 + ((size_t)b * 512 + lo) * 256 + t;
#pragma unroll 4
        for (int l = 0; l < 256; ++l)
            acc = fmaf(wv[lo + l], xp[(size_t)l * 256], acc);
        atomicAdd(&out[(hb * 2 + seg) * 256 + t], acc * inv);
    } else if (t < 192) {
        const float* xp = x2 + ((size_t)b * 512 + lo) * 192 + t;
#pragma unroll 4
        for (int l = 0; l < 256; ++l)
            acc = fmaf(wv[lo + l], xp[(size_t)l * 192], acc);
        atomicAdd(&out[(hb * 2 + seg) * 256 + t], acc * inv);
    } // padded channels >=192 of seg1 stay exactly 0 from k_prep zeroing
}

extern "C" void kernel_launch(void* const* d_in, const int* in_sizes, int n_in,
                              void* d_out, int out_size, void* d_ws, size_t ws_size,
                              hipStream_t stream) {
    const float* x1 = (const float*)d_in[0];
    const float* x2 = (const float*)d_in[1];
    const float* U  = (const float*)d_in[2];
    float* out = (float*)d_out;
    char* wsb  = (char*)d_ws;

    h16*   MHp  = (h16*)(wsb + MH_OFF);
    h16*   MLp  = (h16*)(wsb + ML_OFF);
    h16*   UHt  = (h16*)(wsb + UHT_OFF);
    h16*   ULt  = (h16*)(wsb + ULT_OFF);
    float* rma  = (float*)(wsb + RMA_OFF);
    float* rmh  = (float*)(wsb + RMH_OFF);
    float* pcm  = (float*)(wsb + PCM_OFF);
    int*   m0k  = (int*)(wsb + M0_OFF);

    hipLaunchKernelGGL(k_prep, dim3(8448), dim3(256), 0, stream, x1, x2, U,
                       MHp, MLp, UHt, ULt, m0k, out);
    hipLaunchKernelGGL(k_main, dim3(1024), dim3(1024), 0, stream, MHp, MLp,
                       UHt, ULt, rma, rmh, pcm, m0k);
    hipLaunchKernelGGL(k_fin,  dim3(256),  dim3(256), 0, stream, rma, rmh,
                       pcm, m0k, x1, x2, out);
}

// Round 5
// 318.116 us; speedup vs baseline: 2.6299x; 2.6299x over previous
//
#include <hip/hip_runtime.h>
#include <math.h>

typedef _Float16 h16;
typedef h16  h16x8 __attribute__((ext_vector_type(8)));
typedef h16  h16x4 __attribute__((ext_vector_type(4)));
typedef float f32x4 __attribute__((ext_vector_type(4)));

// ---------------- workspace layout (bytes) ----------------
#define MH_OFF   ((size_t)0)
#define ML_OFF   (MH_OFF + 16777216)
#define UHT_OFF  (ML_OFF + 16777216)
#define ULT_OFF  (UHT_OFF + 262144)
#define RMA_OFF  (ULT_OFF + 262144)
#define RMH_OFF  (RMA_OFF + 262144)
#define PCM_OFF  (RMH_OFF + 262144)
#define M0_OFF   (PCM_OFF + 4194304)

__device__ __forceinline__ float nonsat(float x) {
    float y = x;
#pragma unroll
    for (int i = 0; i < 24; ++i) {
        float y2 = y * y;
        y = fmaf(0.66666667f * y, y2, x) / (y2 + 1.0f);
    }
    return y;
}

__device__ __forceinline__ int fkey(float f) {
    const int i = __float_as_int(f);
    return (i >= 0) ? i : (i ^ 0x7fffffff);
}
__device__ __forceinline__ float funkey(int k) {
    return __int_as_float((k >= 0) ? k : (k ^ 0x7fffffff));
}

// ---------------------------------------------------------------------------
// k_prep: fp16 hi/lo split of virtual M (x2 zero-padded) and of U^T*4.
// ---------------------------------------------------------------------------
__global__ void k_prep(const float* __restrict__ x1, const float* __restrict__ x2,
                       const float* __restrict__ U, h16* __restrict__ MH,
                       h16* __restrict__ ML, h16* __restrict__ UHt,
                       h16* __restrict__ ULt, int* __restrict__ m0key,
                       float* __restrict__ out) {
    const int gid = blockIdx.x * 256 + threadIdx.x;
    if (blockIdx.x < 8192) {
        const int g  = gid;              // (b, j, d4): 32*1024*64 groups
        const int d4 = (g & 63) * 4;
        const int j  = (g >> 6) & 1023;
        const int b  = g >> 16;
        float v[4];
        if (j < 512) {
            const float4 p = *(const float4*)(x1 + ((size_t)(b * 512 + j) * 256 + d4));
            v[0] = p.x; v[1] = p.y; v[2] = p.z; v[3] = p.w;
        } else if (d4 < 192) {
            const float4 p = *(const float4*)(x2 +
                (size_t)(b * 512 + (j - 512)) * 192 + d4);
            v[0] = p.x; v[1] = p.y; v[2] = p.z; v[3] = p.w;
        } else {
            v[0] = v[1] = v[2] = v[3] = 0.0f;
        }
        h16x4 hh, ll;
#pragma unroll
        for (int k = 0; k < 4; ++k) {
            const h16 hi = (h16)v[k];
            hh[k] = hi;
            ll[k] = (h16)(v[k] - (float)hi);
        }
        const size_t o = (size_t)g * 4;
        *(h16x4*)&MH[o] = hh;
        *(h16x4*)&ML[o] = ll;
    } else if (blockIdx.x < 8320) {
        const int g  = gid - 8192 * 256; // U^T: 2*256*64 groups
        const int c4 = (g & 63) * 4;
        const int d  = (g >> 6) & 255;
        const int h  = g >> 14;
        h16x4 hh, ll;
#pragma unroll
        for (int k = 0; k < 4; ++k) {
            const float v = U[((size_t)h * 256 + c4 + k) * 256 + d] * 4.0f;
            const h16 hi = (h16)v;
            hh[k] = hi;
            ll[k] = (h16)(v - (float)hi);
        }
        const size_t o = ((size_t)h * 256 + d) * 256 + c4;
        *(h16x4*)&UHt[o] = hh;
        *(h16x4*)&ULt[o] = ll;
    } else {
        const int z = gid - 8320 * 256;
        out[z] = 0.0f;
        if (z == 0) *m0key = 0x7fffffff;
    }
}

// ---------------------------------------------------------------------------
// k_main (R15): 512-thr / 8-wave blocks, 1 block/CU (136 KB LDS), 256 regs/
// wave budget (launch_bounds(512,2)) — the register conservation law
// (waves/SIMD x regs/wave = 512) makes 4 waves/SIMD unreachable (R14: 64-VGPR
// cap => 900 MB scratch spill). Instead, B-operand latency is removed with
// global_load_lds DMA staging (zero VGPR cost, never blocks the wave):
//   sB[2 dbuf][HL][256 j][32 d] staged one (jt,jtile,kc) slice ahead; the
//   __syncthreads vmcnt-drain (m97 2-phase pattern) guarantees each slice a
//   full compute phase (~900 cyc) >> L2 latency to land. One barrier/step.
// Wave split (wr=w>>2: 32 rows, wj=w&3: 64 j): acc[2][4]=32 AGPR, frags 48
// VGPR -> ~110 regs, no spill. Per-element MFMA order (HH,LH,HL) preserved
// -> bitwise-identical outputs. Quadrant skip kept (jts / do_red).
// ---------------------------------------------------------------------------
__device__ __forceinline__ void stage_b(const h16* __restrict__ MH,
                                        const h16* __restrict__ ML,
                                        h16* sBf, int buf, int b, int jt,
                                        int jtile, int kc, int t, int w) {
    const int jrow0 = jt * 512 + jtile * 256;
#pragma unroll
    for (int g = 0; g < 2; ++g) {   // 2 x 128 j-rows per 16KB plane
        const size_t src = (size_t)(b * 1024 + jrow0 + g * 128 + (t >> 2)) * 256
                           + kc * 32 + (t & 3) * 8;
        h16* dH = sBf + (size_t)(buf * 2 + 0) * 8192 + g * 4096 + w * 512;
        h16* dL = sBf + (size_t)(buf * 2 + 1) * 8192 + g * 4096 + w * 512;
        __builtin_amdgcn_global_load_lds(
            (const __attribute__((address_space(1))) void*)(MH + src),
            (__attribute__((address_space(3))) void*)dH, 16, 0, 0);
        __builtin_amdgcn_global_load_lds(
            (const __attribute__((address_space(1))) void*)(ML + src),
            (__attribute__((address_space(3))) void*)dL, 16, 0, 0);
    }
}

__global__ __launch_bounds__(512, 2)
void k_main(const h16* __restrict__ MH, const h16* __restrict__ ML,
            const h16* __restrict__ UHt, const h16* __restrict__ ULt,
            float* __restrict__ rmax_all, float* __restrict__ rmax_hi,
            float* __restrict__ pcm, int* __restrict__ m0key) {
    __shared__ __align__(16) h16 sP[2][64 * 256];   // P hi/lo, swizzled, 64 KB
    __shared__ __align__(16) h16 sB[2 * 2 * 8192];  // B dbuf, 64 KB
    __shared__ float red[1024 + 8];                 // rowmax slots + gmin
    __shared__ float scm[2][512];                   // colmax partials (2 wr)

    const int n    = blockIdx.x;       // 1024
    const int x    = n & 7;            // XCD-affine swizzle
    const int s    = n >> 3;
    const int b    = x + 8 * (s >> 5);
    const int h    = (s >> 4) & 1;
    const int rblk = s & 15;
    const int hb   = h * 32 + b;
    const int r0   = rblk * 64;
    const int t    = threadIdx.x;
    const int w    = t >> 6;           // wave 0..7
    const int l    = t & 63;
    const int q    = l >> 4;
    const int ln   = l & 15;
    const int wr   = w >> 2;           // row-half 0..1 (32 rows)
    const int wj   = w & 3;            // j-quarter 0..3 (64 j of the 256 tile)

    const int jts    = (h == 1 && rblk < 8) ? 1 : 0;  // head-1 quadrant unused
    const int Usteps = (2 - jts) * 16;                // 2 jtiles x 8 kc per jt

    // prologue: stage step 0 into buf 0 (lands during Phase A)
    stage_b(MH, ML, sB, 0, b, jts, 0, 0, t, w);

    // ---------------- Phase A ----------------
    {
        const int wrA = w >> 2, wcA = w & 3;   // rows wrA*32, cols wcA*64
        f32x4 accA[2][4];
        const f32x4 z4 = {0.f, 0.f, 0.f, 0.f};
#pragma unroll
        for (int i = 0; i < 2; ++i)
#pragma unroll
            for (int j2 = 0; j2 < 4; ++j2) accA[i][j2] = z4;

        for (int kc = 0; kc < 8; ++kc) {
            const int c0 = kc * 32;
            h16x8 aH[2], aL[2], bH[4], bL[4];
#pragma unroll
            for (int ti = 0; ti < 2; ++ti) {
                const size_t off =
                    (size_t)(b * 1024 + r0 + wrA * 32 + ti * 16 + ln) * 256 + c0 + q * 8;
                aH[ti] = *(const h16x8*)&MH[off];
                aL[ti] = *(const h16x8*)&ML[off];
            }
#pragma unroll
            for (int tj = 0; tj < 4; ++tj) {
                const size_t off =
                    (size_t)(h * 256 + wcA * 64 + tj * 16 + ln) * 256 + c0 + q * 8;
                bH[tj] = *(const h16x8*)&UHt[off];
                bL[tj] = *(const h16x8*)&ULt[off];
            }
#pragma unroll
            for (int ti = 0; ti < 2; ++ti)
#pragma unroll
                for (int tj = 0; tj < 4; ++tj)
                    accA[ti][tj] = __builtin_amdgcn_mfma_f32_16x16x32_f16(
                        aH[ti], bH[tj], accA[ti][tj], 0, 0, 0);
#pragma unroll
            for (int ti = 0; ti < 2; ++ti)
#pragma unroll
                for (int tj = 0; tj < 4; ++tj)
                    accA[ti][tj] = __builtin_amdgcn_mfma_f32_16x16x32_f16(
                        aL[ti], bH[tj], accA[ti][tj], 0, 0, 0);
#pragma unroll
            for (int ti = 0; ti < 2; ++ti)
#pragma unroll
                for (int tj = 0; tj < 4; ++tj)
                    accA[ti][tj] = __builtin_amdgcn_mfma_f32_16x16x32_f16(
                        aH[ti], bL[tj], accA[ti][tj], 0, 0, 0);
        }
        // split-store P' into sP, granule-swizzled: gran' = gran ^ (r&7)
#pragma unroll
        for (int ti = 0; ti < 2; ++ti)
#pragma unroll
            for (int tj = 0; tj < 4; ++tj)
#pragma unroll
                for (int reg = 0; reg < 4; ++reg) {
                    const int r = wrA * 32 + ti * 16 + q * 4 + reg;
                    const int d = wcA * 64 + tj * 16 + ln;
                    const float v = accA[ti][tj][reg];
                    const h16 hi = (h16)v;
                    const h16 lo = (h16)(v - (float)hi);
                    const int off = r * 256 + (((d >> 3) ^ (r & 7)) << 3) + (d & 7);
                    sP[0][off] = hi;
                    sP[1][off] = lo;
                }
    }
    __syncthreads();   // sP visible; stage-0 DMA drained (vmcnt(0) in barrier)

    // ---------------- Phase B ----------------
    float gmin = INFINITY;
    float rm[2][4];
    f32x4 acc[2][4];
    const f32x4 z4 = {0.f, 0.f, 0.f, 0.f};
    int cur = 0;

#pragma unroll 1
    for (int u = 0; u < Usteps; ++u) {
        const int jt    = jts + (u >> 4);
        const int jtile = (u >> 3) & 1;
        const int kc    = u & 7;
        const bool dored = (rblk >= 8) || (jt == 1);

        if (u + 1 < Usteps) {
            const int u1 = u + 1;
            stage_b(MH, ML, sB, cur ^ 1, b, jts + (u1 >> 4), (u1 >> 3) & 1,
                    u1 & 7, t, w);
        }
        if (kc == 0) {
#pragma unroll
            for (int i = 0; i < 2; ++i)
#pragma unroll
                for (int j2 = 0; j2 < 4; ++j2) acc[i][j2] = z4;
            if (jtile == 0) {
#pragma unroll
                for (int i = 0; i < 2; ++i)
#pragma unroll
                    for (int j2 = 0; j2 < 4; ++j2) rm[i][j2] = -INFINITY;
            }
        }

        h16x8 aH[2], aL[2], bH[4], bL[4];
#pragma unroll
        for (int ti = 0; ti < 2; ++ti) {
            const int r = wr * 32 + ti * 16 + ln;
            const int g = ((kc * 4 + q) ^ (r & 7)) * 8;
            aH[ti] = *(const h16x8*)&sP[0][r * 256 + g];
            aL[ti] = *(const h16x8*)&sP[1][r * 256 + g];
        }
#pragma unroll
        for (int tj = 0; tj < 4; ++tj) {
            const int jr = wj * 64 + tj * 16 + ln;
            bH[tj] = *(const h16x8*)&sB[(size_t)(cur * 2 + 0) * 8192 + jr * 32 + q * 8];
            bL[tj] = *(const h16x8*)&sB[(size_t)(cur * 2 + 1) * 8192 + jr * 32 + q * 8];
        }
#pragma unroll
        for (int tj = 0; tj < 4; ++tj)
#pragma unroll
            for (int ti = 0; ti < 2; ++ti)
                acc[ti][tj] = __builtin_amdgcn_mfma_f32_16x16x32_f16(
                    aH[ti], bH[tj], acc[ti][tj], 0, 0, 0);
#pragma unroll
        for (int tj = 0; tj < 4; ++tj)
#pragma unroll
            for (int ti = 0; ti < 2; ++ti)
                acc[ti][tj] = __builtin_amdgcn_mfma_f32_16x16x32_f16(
                    aL[ti], bH[tj], acc[ti][tj], 0, 0, 0);
#pragma unroll
        for (int tj = 0; tj < 4; ++tj)
#pragma unroll
            for (int ti = 0; ti < 2; ++ti)
                acc[ti][tj] = __builtin_amdgcn_mfma_f32_16x16x32_f16(
                    aH[ti], bL[tj], acc[ti][tj], 0, 0, 0);

        if (kc == 7) {
            if (dored) {
                // rowmax partial -> rm (accumulated across jtiles)
#pragma unroll
                for (int ti = 0; ti < 2; ++ti)
#pragma unroll
                    for (int reg = 0; reg < 4; ++reg) {
                        float m = acc[ti][0][reg];
#pragma unroll
                        for (int tj = 1; tj < 4; ++tj) m = fmaxf(m, acc[ti][tj][reg]);
                        m = fmaxf(m, __shfl_xor(m, 1));
                        m = fmaxf(m, __shfl_xor(m, 2));
                        m = fmaxf(m, __shfl_xor(m, 4));
                        m = fmaxf(m, __shfl_xor(m, 8));
                        rm[ti][reg] = fmaxf(rm[ti][reg], m);
                    }
                if (jtile == 1) {
#pragma unroll
                    for (int ti = 0; ti < 2; ++ti)
#pragma unroll
                        for (int reg = 0; reg < 4; ++reg)
                            if (ln == 0)
                                red[(jt * 8 + w) * 64 + wr * 32 + ti * 16 +
                                    q * 4 + reg] = rm[ti][reg];
                }
                // colmax over this wave's 32 rows -> scm (q==0 lanes)
#pragma unroll
                for (int tj = 0; tj < 4; ++tj) {
                    float m = -INFINITY;
#pragma unroll
                    for (int ti = 0; ti < 2; ++ti)
#pragma unroll
                        for (int reg = 0; reg < 4; ++reg)
                            m = fmaxf(m, acc[ti][tj][reg]);
                    m = fmaxf(m, __shfl_xor(m, 16));
                    m = fmaxf(m, __shfl_xor(m, 32));
                    if (q == 0)
                        scm[wr][jtile * 256 + wj * 64 + tj * 16 + ln] = m;
                }
            }
            if (h == 0) {
#pragma unroll
                for (int ti = 0; ti < 2; ++ti)
#pragma unroll
                    for (int tj = 0; tj < 4; ++tj)
#pragma unroll
                        for (int reg = 0; reg < 4; ++reg)
                            gmin = fminf(gmin, acc[ti][tj][reg]);
            }
        }
        __syncthreads();   // drains staged DMA (vmcnt 0) + publishes scm
        cur ^= 1;
        if ((u & 15) == 15 && dored) {
            const float v = fmaxf(scm[0][t], scm[1][t]);
            pcm[(size_t)(hb * 16 + rblk) * 1024 + jt * 512 + t] = v * 0.015625f;
        }
    }

    // ---------------- epilogue ----------------
#pragma unroll
    for (int off = 1; off < 64; off <<= 1) gmin = fminf(gmin, __shfl_xor(gmin, off));
    if (l == 0) red[1024 + w] = gmin;
    __syncthreads();

    if (t < 64) {
        const int wrr = t >> 5;
        float hh = -INFINITY;
#pragma unroll
        for (int w2 = 0; w2 < 4; ++w2)
            hh = fmaxf(hh, red[(8 + wrr * 4 + w2) * 64 + t]);   // jt=1
        if (rblk < 8) {
            rmax_hi[(size_t)hb * 1024 + r0 + t] = hh * 0.015625f;
        } else {
            float a = hh;
#pragma unroll
            for (int w2 = 0; w2 < 4; ++w2)
                a = fmaxf(a, red[(wrr * 4 + w2) * 64 + t]);     // jt=0
            rmax_all[(size_t)hb * 1024 + r0 + t] = a * 0.015625f;
        }
    }
    if (t == 0 && hb < 32) {
        float g4 = red[1024];
#pragma unroll
        for (int i = 1; i < 8; ++i) g4 = fminf(g4, red[1024 + i]);
        atomicMin(m0key, fkey(g4 * 0.015625f));
    }
}

// ---------------------------------------------------------------------------
// k_fin: fused alpha (activation post-reduction) + softmax + chunked pooling.
// ---------------------------------------------------------------------------
__global__ __launch_bounds__(256)
void k_fin(const float* __restrict__ rmax_all, const float* __restrict__ rmax_hi,
           const float* __restrict__ pcm, const int* __restrict__ m0key,
           const float* __restrict__ x1, const float* __restrict__ x2,
           float* __restrict__ out) {
    __shared__ float wv[512];
    __shared__ float sm[4], ss[4];
    const int blk   = blockIdx.x;
    const int chunk = blk & 1;
    const int seg   = (blk >> 1) & 1;
    const int hb    = blk >> 2;
    const int b     = hb & 31;
    const int t     = threadIdx.x;
    const float m0  = funkey(*m0key);

    float a2[2];
#pragma unroll
    for (int half = 0; half < 2; ++half) {
        const int i = seg * 512 + half * 256 + t;
        float rraw;
        if (seg == 0) rraw = fmaxf(m0, rmax_hi[(size_t)hb * 1024 + i]);
        else          rraw = rmax_all[(size_t)hb * 1024 + i];
        float call = -INFINITY, chi = -INFINITY;
#pragma unroll
        for (int rb = 0; rb < 16; ++rb) {
            const float v = pcm[(size_t)(hb * 16 + rb) * 1024 + i];
            call = fmaxf(call, v);
            if (rb >= 8) chi = fmaxf(chi, v);
        }
        const float craw = (seg == 0) ? fmaxf(m0, chi) : call;
        a2[half] = nonsat(rraw) + nonsat(craw);
    }
    const float a0 = a2[0], a1 = a2[1];

    float m = fmaxf(a0, a1);
#pragma unroll
    for (int off = 1; off < 64; off <<= 1) m = fmaxf(m, __shfl_xor(m, off));
    if ((t & 63) == 0) sm[t >> 6] = m;
    __syncthreads();
    const float amax = fmaxf(fmaxf(sm[0], sm[1]), fmaxf(sm[2], sm[3]));

    const float e0 = __expf(a0 - amax), e1 = __expf(a1 - amax);
    wv[t] = e0; wv[t + 256] = e1;
    float s = e0 + e1;
#pragma unroll
    for (int off = 1; off < 64; off <<= 1) s += __shfl_xor(s, off);
    if ((t & 63) == 0) ss[t >> 6] = s;
    __syncthreads();
    const float inv = 1.0f / (ss[0] + ss[1] + ss[2] + ss[3]);

    const int lo = chunk * 256;
    float acc = 0.0f;
    if (seg == 0) {
        const float* xp = x1 + ((size_t)b * 512 + lo) * 256 + t;
#pragma unroll 4
        for (int l = 0; l < 256; ++l)
            acc = fmaf(wv[lo + l], xp[(size_t)l * 256], acc);
        atomicAdd(&out[(hb * 2 + seg) * 256 + t], acc * inv);
    } else if (t < 192) {
        const float* xp = x2 + ((size_t)b * 512 + lo) * 192 + t;
#pragma unroll 4
        for (int l = 0; l < 256; ++l)
            acc = fmaf(wv[lo + l], xp[(size_t)l * 192], acc);
        atomicAdd(&out[(hb * 2 + seg) * 256 + t], acc * inv);
    }
}

extern "C" void kernel_launch(void* const* d_in, const int* in_sizes, int n_in,
                              void* d_out, int out_size, void* d_ws, size_t ws_size,
                              hipStream_t stream) {
    const float* x1 = (const float*)d_in[0];
    const float* x2 = (const float*)d_in[1];
    const float* U  = (const float*)d_in[2];
    float* out = (float*)d_out;
    char* wsb  = (char*)d_ws;

    h16*   MHp  = (h16*)(wsb + MH_OFF);
    h16*   MLp  = (h16*)(wsb + ML_OFF);
    h16*   UHt  = (h16*)(wsb + UHT_OFF);
    h16*   ULt  = (h16*)(wsb + ULT_OFF);
    float* rma  = (float*)(wsb + RMA_OFF);
    float* rmh  = (float*)(wsb + RMH_OFF);
    float* pcm  = (float*)(wsb + PCM_OFF);
    int*   m0k  = (int*)(wsb + M0_OFF);

    hipLaunchKernelGGL(k_prep, dim3(8448), dim3(256), 0, stream, x1, x2, U,
                       MHp, MLp, UHt, ULt, m0k, out);
    hipLaunchKernelGGL(k_main, dim3(1024), dim3(512), 0, stream, MHp, MLp,
                       UHt, ULt, rma, rmh, pcm, m0k);
    hipLaunchKernelGGL(k_fin,  dim3(256),  dim3(256), 0, stream, rma, rmh,
                       pcm, m0k, x1, x2, out);
}

// Round 6
// 314.448 us; speedup vs baseline: 2.6606x; 1.0117x over previous
//
#include <hip/hip_runtime.h>
#include <math.h>

typedef _Float16 h16;
typedef h16  h16x8 __attribute__((ext_vector_type(8)));
typedef h16  h16x4 __attribute__((ext_vector_type(4)));
typedef float f32x4 __attribute__((ext_vector_type(4)));

// ---------------- workspace layout (bytes) ----------------
#define MH_OFF   ((size_t)0)
#define ML_OFF   (MH_OFF + 16777216)
#define UHT_OFF  (ML_OFF + 16777216)
#define ULT_OFF  (UHT_OFF + 262144)
#define RMA_OFF  (ULT_OFF + 262144)
#define RMH_OFF  (RMA_OFF + 262144)
#define PCM_OFF  (RMH_OFF + 262144)
#define M0_OFF   (PCM_OFF + 4194304)

__device__ __forceinline__ float nonsat(float x) {
    float y = x;
#pragma unroll
    for (int i = 0; i < 24; ++i) {
        float y2 = y * y;
        y = fmaf(0.66666667f * y, y2, x) / (y2 + 1.0f);
    }
    return y;
}

__device__ __forceinline__ int fkey(float f) {
    const int i = __float_as_int(f);
    return (i >= 0) ? i : (i ^ 0x7fffffff);
}
__device__ __forceinline__ float funkey(int k) {
    return __int_as_float((k >= 0) ? k : (k ^ 0x7fffffff));
}

// ---------------------------------------------------------------------------
// k_prep: fp16 hi/lo split of virtual M (x2 zero-padded) and of U^T*4.
// ---------------------------------------------------------------------------
__global__ void k_prep(const float* __restrict__ x1, const float* __restrict__ x2,
                       const float* __restrict__ U, h16* __restrict__ MH,
                       h16* __restrict__ ML, h16* __restrict__ UHt,
                       h16* __restrict__ ULt, int* __restrict__ m0key,
                       float* __restrict__ out) {
    const int gid = blockIdx.x * 256 + threadIdx.x;
    if (blockIdx.x < 8192) {
        const int g  = gid;              // (b, j, d4): 32*1024*64 groups
        const int d4 = (g & 63) * 4;
        const int j  = (g >> 6) & 1023;
        const int b  = g >> 16;
        float v[4];
        if (j < 512) {
            const float4 p = *(const float4*)(x1 + ((size_t)(b * 512 + j) * 256 + d4));
            v[0] = p.x; v[1] = p.y; v[2] = p.z; v[3] = p.w;
        } else if (d4 < 192) {
            const float4 p = *(const float4*)(x2 +
                (size_t)(b * 512 + (j - 512)) * 192 + d4);
            v[0] = p.x; v[1] = p.y; v[2] = p.z; v[3] = p.w;
        } else {
            v[0] = v[1] = v[2] = v[3] = 0.0f;
        }
        h16x4 hh, ll;
#pragma unroll
        for (int k = 0; k < 4; ++k) {
            const h16 hi = (h16)v[k];
            hh[k] = hi;
            ll[k] = (h16)(v[k] - (float)hi);
        }
        const size_t o = (size_t)g * 4;
        *(h16x4*)&MH[o] = hh;
        *(h16x4*)&ML[o] = ll;
    } else if (blockIdx.x < 8320) {
        const int g  = gid - 8192 * 256; // U^T: 2*256*64 groups
        const int c4 = (g & 63) * 4;
        const int d  = (g >> 6) & 255;
        const int h  = g >> 14;
        h16x4 hh, ll;
#pragma unroll
        for (int k = 0; k < 4; ++k) {
            const float v = U[((size_t)h * 256 + c4 + k) * 256 + d] * 4.0f;
            const h16 hi = (h16)v;
            hh[k] = hi;
            ll[k] = (h16)(v - (float)hi);
        }
        const size_t o = ((size_t)h * 256 + d) * 256 + c4;
        *(h16x4*)&UHt[o] = hh;
        *(h16x4*)&ULt[o] = ll;
    } else {
        const int z = gid - 8320 * 256;
        out[z] = 0.0f;
        if (z == 0) *m0key = 0x7fffffff;
    }
}

// ---------------------------------------------------------------------------
// k_main (R16 = R15 + sB bank-conflict swizzle). R5 post-mortem: DMA staging
// worked (FETCH 18.5 MB, WRITE 3.3 MB, no spill) but SQ_LDS_BANK_CONFLICT
// rose 5x to 1.1e7 — sB's [256 j][32 d] rows are 64 B, so a quad's 16 lanes
// reading consecutive rows at the same 16B chunk alias banks 8-way (rows
// stride 16 banks). Fix per T2 + rule #21 (global_load_lds writes linearly:
// swizzle BOTH the per-lane global source and the read address with the same
// involution): 16B-chunk slot s = c ^ ((row>>1)&3). Read banks become
// p*16 + (q^(m&3))*4 -> 8 banks x 2 lanes = 2-way (free, m136). Values are
// identical -> bitwise-identical outputs. Everything else unchanged from R15.
// ---------------------------------------------------------------------------
__device__ __forceinline__ void stage_b(const h16* __restrict__ MH,
                                        const h16* __restrict__ ML,
                                        h16* sBf, int buf, int b, int jt,
                                        int jtile, int kc, int t, int w) {
    const int jrow0 = jt * 512 + jtile * 256;
    // lane's LDS landing slot: row = g*128 + (t>>2), 16B-chunk slot s = t&3.
    // logical chunk c placed there: c = s ^ ((row>>1)&3) = (t&3) ^ ((t>>3)&3).
    const int c = (t & 3) ^ ((t >> 3) & 3);
#pragma unroll
    for (int g = 0; g < 2; ++g) {   // 2 x 128 j-rows per 16KB plane
        const size_t src = (size_t)(b * 1024 + jrow0 + g * 128 + (t >> 2)) * 256
                           + kc * 32 + c * 8;
        h16* dH = sBf + (size_t)(buf * 2 + 0) * 8192 + g * 4096 + w * 512;
        h16* dL = sBf + (size_t)(buf * 2 + 1) * 8192 + g * 4096 + w * 512;
        __builtin_amdgcn_global_load_lds(
            (const __attribute__((address_space(1))) void*)(MH + src),
            (__attribute__((address_space(3))) void*)dH, 16, 0, 0);
        __builtin_amdgcn_global_load_lds(
            (const __attribute__((address_space(1))) void*)(ML + src),
            (__attribute__((address_space(3))) void*)dL, 16, 0, 0);
    }
}

__global__ __launch_bounds__(512, 2)
void k_main(const h16* __restrict__ MH, const h16* __restrict__ ML,
            const h16* __restrict__ UHt, const h16* __restrict__ ULt,
            float* __restrict__ rmax_all, float* __restrict__ rmax_hi,
            float* __restrict__ pcm, int* __restrict__ m0key) {
    __shared__ __align__(16) h16 sP[2][64 * 256];   // P hi/lo, swizzled, 64 KB
    __shared__ __align__(16) h16 sB[2 * 2 * 8192];  // B dbuf, 64 KB
    __shared__ float red[1024 + 8];                 // rowmax slots + gmin
    __shared__ float scm[2][512];                   // colmax partials (2 wr)

    const int n    = blockIdx.x;       // 1024
    const int x    = n & 7;            // XCD-affine swizzle
    const int s    = n >> 3;
    const int b    = x + 8 * (s >> 5);
    const int h    = (s >> 4) & 1;
    const int rblk = s & 15;
    const int hb   = h * 32 + b;
    const int r0   = rblk * 64;
    const int t    = threadIdx.x;
    const int w    = t >> 6;           // wave 0..7
    const int l    = t & 63;
    const int q    = l >> 4;
    const int ln   = l & 15;
    const int wr   = w >> 2;           // row-half 0..1 (32 rows)
    const int wj   = w & 3;            // j-quarter 0..3 (64 j of the 256 tile)

    const int jts    = (h == 1 && rblk < 8) ? 1 : 0;  // head-1 quadrant unused
    const int Usteps = (2 - jts) * 16;                // 2 jtiles x 8 kc per jt

    // prologue: stage step 0 into buf 0 (lands during Phase A)
    stage_b(MH, ML, sB, 0, b, jts, 0, 0, t, w);

    // ---------------- Phase A ----------------
    {
        const int wrA = w >> 2, wcA = w & 3;   // rows wrA*32, cols wcA*64
        f32x4 accA[2][4];
        const f32x4 z4 = {0.f, 0.f, 0.f, 0.f};
#pragma unroll
        for (int i = 0; i < 2; ++i)
#pragma unroll
            for (int j2 = 0; j2 < 4; ++j2) accA[i][j2] = z4;

        for (int kc = 0; kc < 8; ++kc) {
            const int c0 = kc * 32;
            h16x8 aH[2], aL[2], bH[4], bL[4];
#pragma unroll
            for (int ti = 0; ti < 2; ++ti) {
                const size_t off =
                    (size_t)(b * 1024 + r0 + wrA * 32 + ti * 16 + ln) * 256 + c0 + q * 8;
                aH[ti] = *(const h16x8*)&MH[off];
                aL[ti] = *(const h16x8*)&ML[off];
            }
#pragma unroll
            for (int tj = 0; tj < 4; ++tj) {
                const size_t off =
                    (size_t)(h * 256 + wcA * 64 + tj * 16 + ln) * 256 + c0 + q * 8;
                bH[tj] = *(const h16x8*)&UHt[off];
                bL[tj] = *(const h16x8*)&ULt[off];
            }
#pragma unroll
            for (int ti = 0; ti < 2; ++ti)
#pragma unroll
                for (int tj = 0; tj < 4; ++tj)
                    accA[ti][tj] = __builtin_amdgcn_mfma_f32_16x16x32_f16(
                        aH[ti], bH[tj], accA[ti][tj], 0, 0, 0);
#pragma unroll
            for (int ti = 0; ti < 2; ++ti)
#pragma unroll
                for (int tj = 0; tj < 4; ++tj)
                    accA[ti][tj] = __builtin_amdgcn_mfma_f32_16x16x32_f16(
                        aL[ti], bH[tj], accA[ti][tj], 0, 0, 0);
#pragma unroll
            for (int ti = 0; ti < 2; ++ti)
#pragma unroll
                for (int tj = 0; tj < 4; ++tj)
                    accA[ti][tj] = __builtin_amdgcn_mfma_f32_16x16x32_f16(
                        aH[ti], bL[tj], accA[ti][tj], 0, 0, 0);
        }
        // split-store P' into sP, granule-swizzled: gran' = gran ^ (r&7)
#pragma unroll
        for (int ti = 0; ti < 2; ++ti)
#pragma unroll
            for (int tj = 0; tj < 4; ++tj)
#pragma unroll
                for (int reg = 0; reg < 4; ++reg) {
                    const int r = wrA * 32 + ti * 16 + q * 4 + reg;
                    const int d = wcA * 64 + tj * 16 + ln;
                    const float v = accA[ti][tj][reg];
                    const h16 hi = (h16)v;
                    const h16 lo = (h16)(v - (float)hi);
                    const int off = r * 256 + (((d >> 3) ^ (r & 7)) << 3) + (d & 7);
                    sP[0][off] = hi;
                    sP[1][off] = lo;
                }
    }
    __syncthreads();   // sP visible; stage-0 DMA drained (vmcnt(0) in barrier)

    // ---------------- Phase B ----------------
    float gmin = INFINITY;
    float rm[2][4];
    f32x4 acc[2][4];
    const f32x4 z4 = {0.f, 0.f, 0.f, 0.f};
    int cur = 0;

#pragma unroll 1
    for (int u = 0; u < Usteps; ++u) {
        const int jt    = jts + (u >> 4);
        const int jtile = (u >> 3) & 1;
        const int kc    = u & 7;
        const bool dored = (rblk >= 8) || (jt == 1);

        if (u + 1 < Usteps) {
            const int u1 = u + 1;
            stage_b(MH, ML, sB, cur ^ 1, b, jts + (u1 >> 4), (u1 >> 3) & 1,
                    u1 & 7, t, w);
        }
        if (kc == 0) {
#pragma unroll
            for (int i = 0; i < 2; ++i)
#pragma unroll
                for (int j2 = 0; j2 < 4; ++j2) acc[i][j2] = z4;
            if (jtile == 0) {
#pragma unroll
                for (int i = 0; i < 2; ++i)
#pragma unroll
                    for (int j2 = 0; j2 < 4; ++j2) rm[i][j2] = -INFINITY;
            }
        }

        h16x8 aH[2], aL[2], bH[4], bL[4];
#pragma unroll
        for (int ti = 0; ti < 2; ++ti) {
            const int r = wr * 32 + ti * 16 + ln;
            const int g = ((kc * 4 + q) ^ (r & 7)) * 8;
            aH[ti] = *(const h16x8*)&sP[0][r * 256 + g];
            aL[ti] = *(const h16x8*)&sP[1][r * 256 + g];
        }
#pragma unroll
        for (int tj = 0; tj < 4; ++tj) {
            const int jr = wj * 64 + tj * 16 + ln;
            const int cp = (q ^ ((jr >> 1) & 3)) * 8;   // swizzled 16B chunk
            bH[tj] = *(const h16x8*)&sB[(size_t)(cur * 2 + 0) * 8192 + jr * 32 + cp];
            bL[tj] = *(const h16x8*)&sB[(size_t)(cur * 2 + 1) * 8192 + jr * 32 + cp];
        }
#pragma unroll
        for (int tj = 0; tj < 4; ++tj)
#pragma unroll
            for (int ti = 0; ti < 2; ++ti)
                acc[ti][tj] = __builtin_amdgcn_mfma_f32_16x16x32_f16(
                    aH[ti], bH[tj], acc[ti][tj], 0, 0, 0);
#pragma unroll
        for (int tj = 0; tj < 4; ++tj)
#pragma unroll
            for (int ti = 0; ti < 2; ++ti)
                acc[ti][tj] = __builtin_amdgcn_mfma_f32_16x16x32_f16(
                    aL[ti], bH[tj], acc[ti][tj], 0, 0, 0);
#pragma unroll
        for (int tj = 0; tj < 4; ++tj)
#pragma unroll
            for (int ti = 0; ti < 2; ++ti)
                acc[ti][tj] = __builtin_amdgcn_mfma_f32_16x16x32_f16(
                    aH[ti], bL[tj], acc[ti][tj], 0, 0, 0);

        if (kc == 7) {
            if (dored) {
                // rowmax partial -> rm (accumulated across jtiles)
#pragma unroll
                for (int ti = 0; ti < 2; ++ti)
#pragma unroll
                    for (int reg = 0; reg < 4; ++reg) {
                        float m = acc[ti][0][reg];
#pragma unroll
                        for (int tj = 1; tj < 4; ++tj) m = fmaxf(m, acc[ti][tj][reg]);
                        m = fmaxf(m, __shfl_xor(m, 1));
                        m = fmaxf(m, __shfl_xor(m, 2));
                        m = fmaxf(m, __shfl_xor(m, 4));
                        m = fmaxf(m, __shfl_xor(m, 8));
                        rm[ti][reg] = fmaxf(rm[ti][reg], m);
                    }
                if (jtile == 1) {
#pragma unroll
                    for (int ti = 0; ti < 2; ++ti)
#pragma unroll
                        for (int reg = 0; reg < 4; ++reg)
                            if (ln == 0)
                                red[(jt * 8 + w) * 64 + wr * 32 + ti * 16 +
                                    q * 4 + reg] = rm[ti][reg];
                }
                // colmax over this wave's 32 rows -> scm (q==0 lanes)
#pragma unroll
                for (int tj = 0; tj < 4; ++tj) {
                    float m = -INFINITY;
#pragma unroll
                    for (int ti = 0; ti < 2; ++ti)
#pragma unroll
                        for (int reg = 0; reg < 4; ++reg)
                            m = fmaxf(m, acc[ti][tj][reg]);
                    m = fmaxf(m, __shfl_xor(m, 16));
                    m = fmaxf(m, __shfl_xor(m, 32));
                    if (q == 0)
                        scm[wr][jtile * 256 + wj * 64 + tj * 16 + ln] = m;
                }
            }
            if (h == 0) {
#pragma unroll
                for (int ti = 0; ti < 2; ++ti)
#pragma unroll
                    for (int tj = 0; tj < 4; ++tj)
#pragma unroll
                        for (int reg = 0; reg < 4; ++reg)
                            gmin = fminf(gmin, acc[ti][tj][reg]);
            }
        }
        __syncthreads();   // drains staged DMA (vmcnt 0) + publishes scm
        cur ^= 1;
        if ((u & 15) == 15 && dored) {
            const float v = fmaxf(scm[0][t], scm[1][t]);
            pcm[(size_t)(hb * 16 + rblk) * 1024 + jt * 512 + t] = v * 0.015625f;
        }
    }

    // ---------------- epilogue ----------------
#pragma unroll
    for (int off = 1; off < 64; off <<= 1) gmin = fminf(gmin, __shfl_xor(gmin, off));
    if (l == 0) red[1024 + w] = gmin;
    __syncthreads();

    if (t < 64) {
        const int wrr = t >> 5;
        float hh = -INFINITY;
#pragma unroll
        for (int w2 = 0; w2 < 4; ++w2)
            hh = fmaxf(hh, red[(8 + wrr * 4 + w2) * 64 + t]);   // jt=1
        if (rblk < 8) {
            rmax_hi[(size_t)hb * 1024 + r0 + t] = hh * 0.015625f;
        } else {
            float a = hh;
#pragma unroll
            for (int w2 = 0; w2 < 4; ++w2)
                a = fmaxf(a, red[(wrr * 4 + w2) * 64 + t]);     // jt=0
            rmax_all[(size_t)hb * 1024 + r0 + t] = a * 0.015625f;
        }
    }
    if (t == 0 && hb < 32) {
        float g4 = red[1024];
#pragma unroll
        for (int i = 1; i < 8; ++i) g4 = fminf(g4, red[1024 + i]);
        atomicMin(m0key, fkey(g4 * 0.015625f));
    }
}

// ---------------------------------------------------------------------------
// k_fin: fused alpha (activation post-reduction) + softmax + chunked pooling.
// ---------------------------------------------------------------------------
__global__ __launch_bounds__(256)
void k_fin(const float* __restrict__ rmax_all, const float* __restrict__ rmax_hi,
           const float* __restrict__ pcm, const int* __restrict__ m0key,
           const float* __restrict__ x1, const float* __restrict__ x2,
           float* __restrict__ out) {
    __shared__ float wv[512];
    __shared__ float sm[4], ss[4];
    const int blk   = blockIdx.x;
    const int chunk = blk & 1;
    const int seg   = (blk >> 1) & 1;
    const int hb    = blk >> 2;
    const int b     = hb & 31;
    const int t     = threadIdx.x;
    const float m0  = funkey(*m0key);

    float a2[2];
#pragma unroll
    for (int half = 0; half < 2; ++half) {
        const int i = seg * 512 + half * 256 + t;
        float rraw;
        if (seg == 0) rraw = fmaxf(m0, rmax_hi[(size_t)hb * 1024 + i]);
        else          rraw = rmax_all[(size_t)hb * 1024 + i];
        float call = -INFINITY, chi = -INFINITY;
#pragma unroll
        for (int rb = 0; rb < 16; ++rb) {
            const float v = pcm[(size_t)(hb * 16 + rb) * 1024 + i];
            call = fmaxf(call, v);
            if (rb >= 8) chi = fmaxf(chi, v);
        }
        const float craw = (seg == 0) ? fmaxf(m0, chi) : call;
        a2[half] = nonsat(rraw) + nonsat(craw);
    }
    const float a0 = a2[0], a1 = a2[1];

    float m = fmaxf(a0, a1);
#pragma unroll
    for (int off = 1; off < 64; off <<= 1) m = fmaxf(m, __shfl_xor(m, off));
    if ((t & 63) == 0) sm[t >> 6] = m;
    __syncthreads();
    const float amax = fmaxf(fmaxf(sm[0], sm[1]), fmaxf(sm[2], sm[3]));

    const float e0 = __expf(a0 - amax), e1 = __expf(a1 - amax);
    wv[t] = e0; wv[t + 256] = e1;
    float s = e0 + e1;
#pragma unroll
    for (int off = 1; off < 64; off <<= 1) s += __shfl_xor(s, off);
    if ((t & 63) == 0) ss[t >> 6] = s;
    __syncthreads();
    const float inv = 1.0f / (ss[0] + ss[1] + ss[2] + ss[3]);

    const int lo = chunk * 256;
    float acc = 0.0f;
    if (seg == 0) {
        const float* xp = x1 + ((size_t)b * 512 + lo) * 256 + t;
#pragma unroll 4
        for (int l = 0; l < 256; ++l)
            acc = fmaf(wv[lo + l], xp[(size_t)l * 256], acc);
        atomicAdd(&out[(hb * 2 + seg) * 256 + t], acc * inv);
    } else if (t < 192) {
        const float* xp = x2 + ((size_t)b * 512 + lo) * 192 + t;
#pragma unroll 4
        for (int l = 0; l < 256; ++l)
            acc = fmaf(wv[lo + l], xp[(size_t)l * 192], acc);
        atomicAdd(&out[(hb * 2 + seg) * 256 + t], acc * inv);
    }
}

extern "C" void kernel_launch(void* const* d_in, const int* in_sizes, int n_in,
                              void* d_out, int out_size, void* d_ws, size_t ws_size,
                              hipStream_t stream) {
    const float* x1 = (const float*)d_in[0];
    const float* x2 = (const float*)d_in[1];
    const float* U  = (const float*)d_in[2];
    float* out = (float*)d_out;
    char* wsb  = (char*)d_ws;

    h16*   MHp  = (h16*)(wsb + MH_OFF);
    h16*   MLp  = (h16*)(wsb + ML_OFF);
    h16*   UHt  = (h16*)(wsb + UHT_OFF);
    h16*   ULt  = (h16*)(wsb + ULT_OFF);
    float* rma  = (float*)(wsb + RMA_OFF);
    float* rmh  = (float*)(wsb + RMH_OFF);
    float* pcm  = (float*)(wsb + PCM_OFF);
    int*   m0k  = (int*)(wsb + M0_OFF);

    hipLaunchKernelGGL(k_prep, dim3(8448), dim3(256), 0, stream, x1, x2, U,
                       MHp, MLp, UHt, ULt, m0k, out);
    hipLaunchKernelGGL(k_main, dim3(1024), dim3(512), 0, stream, MHp, MLp,
                       UHt, ULt, rma, rmh, pcm, m0k);
    hipLaunchKernelGGL(k_fin,  dim3(256),  dim3(256), 0, stream, rma, rmh,
                       pcm, m0k, x1, x2, out);
}